// Round 1
// baseline (320.513 us; speedup 1.0000x reference)
//
#include <hip/hip_runtime.h>
#include <stdint.h>

#define B_ 64
#define C_ 4
#define R_ 64
#define E_ 512
#define P_ 4
#define OS_ 256
#define L_ (R_*E_)        // 32768
#define K_ (L_*P_)        // 131072
#define M_ (B_*C_)        // 256

#define BM 128
#define BN 128
#define BK 32
#define KCH 2048          // K per block; KSPLIT = K_/KCH = 64
#define AS_STR 40         // bf16 elems per LDS row (pad 32->40, 80 B)
#define WS_STR 36         // f32 elems per LDS row (pad 32->36, 144 B)

typedef float  floatx4 __attribute__((ext_vector_type(4)));
typedef short  shortx8 __attribute__((ext_vector_type(8)));

static __device__ __forceinline__ unsigned short f2bf(float f) {
  union { float f; unsigned int u; } v; v.f = f;
  unsigned int u = v.u;
  u += 0x7fffu + ((u >> 16) & 1u);   // RNE; NaN irrelevant here
  return (unsigned short)(u >> 16);
}

// One block per (b,c,r): gather + sign + pool -> bf16 row segment of A.
__global__ __launch_bounds__(512) void build_A(
    const float* __restrict__ x, const int* __restrict__ rxd_perm,
    const int* __restrict__ e_idx, const float* __restrict__ signs,
    unsigned short* __restrict__ A) {
  const int bcr = blockIdx.x;
  const int r  = bcr & (R_ - 1);
  const int bc = bcr >> 6;
  const int e  = threadIdx.x;
  __shared__ float xr[E_];
  __shared__ float vbuf[E_];
  const int pr = rxd_perm[r];
  xr[e] = x[((size_t)bc * R_ + pr) * E_ + e];
  __syncthreads();
  #pragma unroll
  for (int p = 0; p < P_; ++p) {
    const float v = xr[e_idx[e * P_ + p]] * signs[e * P_ + p];
    vbuf[e] = v;
    __syncthreads();
    float outv = v;
    if (p > 0) {
      const int k = 1 << p;
      const int base = e & ~(k - 1);
      float m = vbuf[base]; int am = base;
      for (int j = 1; j < k; ++j) {
        float t = vbuf[base + j];
        if (t > m) { m = t; am = base + j; }   // strict > == first argmax
      }
      outv = (e == am) ? v : 0.0f;
    }
    A[(size_t)bc * K_ + (size_t)p * L_ + r * E_ + e] = f2bf(outv);
    __syncthreads();
  }
}

__global__ void init_out(const float* __restrict__ bias, float* __restrict__ out) {
  const int i = blockIdx.x * blockDim.x + threadIdx.x;
  out[i] = bias[i & (OS_ - 1)];
}

// Split-K GEMM: C[m,n] += sum_k A_bf16[m,k] * bf16(W[n,k]); atomic fp32 accumulate.
__global__ __launch_bounds__(256) void gemm_splitk(
    const unsigned short* __restrict__ A, const float* __restrict__ W,
    float* __restrict__ out) {
  __shared__ unsigned short As[BM * AS_STR];
  __shared__ float Ws[BN * WS_STR];
  const int t    = threadIdx.x;
  const int lane = t & 63;
  const int wv   = t >> 6;
  const int mBase = blockIdx.x * BM;
  const int nBase = blockIdx.y * BN;
  const int k0base = blockIdx.z * KCH;

  const int wm   = (wv >> 1) * 64;
  const int wn   = (wv & 1) * 64;
  const int lrow = lane & 15;
  const int quad = lane >> 4;
  const int ks   = quad * 8;

  floatx4 acc[4][4];
  #pragma unroll
  for (int i = 0; i < 4; ++i)
    #pragma unroll
    for (int j = 0; j < 4; ++j)
      acc[i][j] = {0.f, 0.f, 0.f, 0.f};

  for (int kk = 0; kk < KCH; kk += BK) {
    const int k0 = k0base + kk;
    // stage A tile: 128 rows x 32 bf16 (2 rounds x 256 thr x 16 B)
    #pragma unroll
    for (int i = 0; i < 2; ++i) {
      const int fc = i * 256 + t;
      const int row = fc >> 2, ch = fc & 3;
      uint4 d = *(const uint4*)(A + (size_t)(mBase + row) * K_ + k0 + ch * 8);
      *(uint4*)(As + row * AS_STR + ch * 8) = d;
    }
    // stage W tile: 128 rows x 32 f32 (4 rounds x 256 thr x 16 B)
    #pragma unroll
    for (int i = 0; i < 4; ++i) {
      const int fc = i * 256 + t;
      const int row = fc >> 3, ch = fc & 7;
      float4 d = *(const float4*)(W + (size_t)(nBase + row) * K_ + k0 + ch * 4);
      *(float4*)(Ws + row * WS_STR + ch * 4) = d;
    }
    __syncthreads();

    shortx8 af[4];
    #pragma unroll
    for (int ti = 0; ti < 4; ++ti)
      af[ti] = *(const shortx8*)(As + (wm + ti * 16 + lrow) * AS_STR + ks);

    #pragma unroll
    for (int tj = 0; tj < 4; ++tj) {
      const float* wrow = Ws + (wn + tj * 16 + lrow) * WS_STR + ks;
      const float4 w0 = *(const float4*)(wrow);
      const float4 w1 = *(const float4*)(wrow + 4);
      shortx8 bf;
      bf[0] = (short)f2bf(w0.x); bf[1] = (short)f2bf(w0.y);
      bf[2] = (short)f2bf(w0.z); bf[3] = (short)f2bf(w0.w);
      bf[4] = (short)f2bf(w1.x); bf[5] = (short)f2bf(w1.y);
      bf[6] = (short)f2bf(w1.z); bf[7] = (short)f2bf(w1.w);
      #pragma unroll
      for (int ti = 0; ti < 4; ++ti)
        acc[ti][tj] = __builtin_amdgcn_mfma_f32_16x16x32_bf16(af[ti], bf, acc[ti][tj], 0, 0, 0);
    }
    __syncthreads();
  }

  // epilogue: atomic accumulate partials (D layout: m = quad*4+reg, n = lane&15)
  #pragma unroll
  for (int ti = 0; ti < 4; ++ti)
    #pragma unroll
    for (int tj = 0; tj < 4; ++tj)
      #pragma unroll
      for (int j = 0; j < 4; ++j) {
        const int m = mBase + wm + ti * 16 + quad * 4 + j;
        const int n = nBase + wn + tj * 16 + lrow;
        atomicAdd(out + (size_t)m * OS_ + n, acc[ti][tj][j]);
      }
}

extern "C" void kernel_launch(void* const* d_in, const int* in_sizes, int n_in,
                              void* d_out, int out_size, void* d_ws, size_t ws_size,
                              hipStream_t stream) {
  const float* x        = (const float*)d_in[0];
  const int*   rxd_perm = (const int*)d_in[1];
  const int*   e_idx    = (const int*)d_in[2];
  const float* signs    = (const float*)d_in[3];
  const float* W        = (const float*)d_in[4];
  const float* bias     = (const float*)d_in[5];
  float* out = (float*)d_out;
  unsigned short* A = (unsigned short*)d_ws;   // 256 x 131072 bf16 = 67.1 MB

  build_A<<<dim3(B_ * C_ * R_), dim3(512), 0, stream>>>(x, rxd_perm, e_idx, signs, A);
  init_out<<<dim3((OS_ * M_) / 256), dim3(256), 0, stream>>>(bias, out);
  gemm_splitk<<<dim3(M_ / BM, OS_ / BN, K_ / KCH), dim3(256), 0, stream>>>(A, W, out);
}

// Round 2
// 305.314 us; speedup vs baseline: 1.0498x; 1.0498x over previous
//
#include <hip/hip_runtime.h>
#include <stdint.h>

#define B_ 64
#define C_ 4
#define R_ 64
#define E_ 512
#define P_ 4
#define OS_ 256
#define L_ (R_*E_)        // 32768
#define K_ (L_*P_)        // 131072
#define M_ (B_*C_)        // 256

#define BM 128
#define BN 128
#define BK 32

typedef float  floatx4 __attribute__((ext_vector_type(4)));
typedef short  shortx8 __attribute__((ext_vector_type(8)));

static __device__ __forceinline__ unsigned short f2bf(float f) {
  union { float f; unsigned int u; } v; v.f = f;
  unsigned int u = v.u;
  u += 0x7fffu + ((u >> 16) & 1u);   // RNE
  return (unsigned short)(u >> 16);
}

// LDS tile granule index (16-B granules). Swizzle ^ (ch<<2) makes BOTH the
// staging writes (quarter-wave = 4 rows x 4 ch -> 2-way, free) and the
// fragment reads (quarter-wave = quad, 16 rows -> 8 distinct bank starts,
// 2-way, free) conflict-free.
static __device__ __forceinline__ int gidx(int row, int ch) {
  return (row >> 4) * 64 + ch * 16 + ((row & 15) ^ (ch << 2));
}

// One block per (bc, r): stage x-row in LDS (1 barrier), gather+sign, pool
// via in-wave shuffle tournaments (k<=8 fits in a wave), coalesced bf16 stores.
__global__ __launch_bounds__(512) void build_A(
    const float* __restrict__ x, const int* __restrict__ rxd_perm,
    const int* __restrict__ e_idx, const float* __restrict__ signs,
    unsigned short* __restrict__ A) {
  const int bcr = blockIdx.x;          // 16384 = 256 bc * 64 r
  const int r  = bcr & (R_ - 1);
  const int bc = bcr >> 6;
  const int e  = threadIdx.x;          // 0..511
  __shared__ float xr[E_];
  xr[e] = x[((size_t)(bc * R_ + rxd_perm[r])) * E_ + e];
  __syncthreads();

  const uint4  ei = *(const uint4*)(e_idx + e * 4);
  const float4 sg = *(const float4*)(signs + e * 4);
  const float v0 = xr[ei.x] * sg.x;
  const float v1 = xr[ei.y] * sg.y;
  const float v2 = xr[ei.z] * sg.z;
  const float v3 = xr[ei.w] * sg.w;

  unsigned short* dst = A + (size_t)bc * K_ + r * E_ + e;
  dst[0] = f2bf(v0);

  // p=1 (k=2): keep iff this lane is the first argmax of its pair
  {
    const float ov = __shfl_xor(v1, 1, 64);
    const bool keep = (e & 1) ? (v1 > ov) : (v1 >= ov);
    dst[L_] = f2bf(keep ? v1 : 0.0f);
  }
  // p=2 (k=4): (value, index) tournament, first-max tie-break
  {
    float m = v2; int mi = e;
    #pragma unroll
    for (int d = 1; d <= 2; d <<= 1) {
      const float om  = __shfl_xor(m, d, 64);
      const int   omi = __shfl_xor(mi, d, 64);
      const bool take = (om > m) || (om == m && omi < mi);
      m = take ? om : m; mi = take ? omi : mi;
    }
    dst[2 * L_] = f2bf((mi == e) ? v2 : 0.0f);
  }
  // p=3 (k=8)
  {
    float m = v3; int mi = e;
    #pragma unroll
    for (int d = 1; d <= 4; d <<= 1) {
      const float om  = __shfl_xor(m, d, 64);
      const int   omi = __shfl_xor(mi, d, 64);
      const bool take = (om > m) || (om == m && omi < mi);
      m = take ? om : m; mi = take ? omi : mi;
    }
    dst[3 * L_] = f2bf((mi == e) ? v3 : 0.0f);
  }
}

__global__ void init_out(const float* __restrict__ bias, float* __restrict__ out) {
  const int i = blockIdx.x * blockDim.x + threadIdx.x;
  out[i] = bias[i & (OS_ - 1)];
}

// Split-K GEMM. atomic_mode=0: write per-z partials (no atomics).
// atomic_mode=1: atomicAdd into bias-initialized out.
__global__ __launch_bounds__(256, 4) void gemm_splitk(
    const unsigned short* __restrict__ A, const float* __restrict__ W,
    float* __restrict__ out, int kch, int atomic_mode) {
  __shared__ unsigned short As[BM * BK];   // 8 KB, swizzled granules
  __shared__ unsigned short Ws[BN * BK];   // 8 KB (bf16-converted at stage)
  const int t    = threadIdx.x;
  const int lane = t & 63;
  const int wv   = t >> 6;
  const int mBase = blockIdx.x * BM;
  const int nBase = blockIdx.y * BN;
  const size_t k0base = (size_t)blockIdx.z * kch;

  const int wm   = (wv >> 1) * 64;
  const int wn   = (wv & 1) * 64;
  const int lrow = lane & 15;
  const int quad = lane >> 4;
  const int srow = t >> 2;       // staging: 4 lanes per row (64B A / 128B W)
  const int sch  = t & 3;

  floatx4 acc[4][4];
  #pragma unroll
  for (int i = 0; i < 4; ++i)
    #pragma unroll
    for (int j = 0; j < 4; ++j)
      acc[i][j] = {0.f, 0.f, 0.f, 0.f};

  for (int kk = 0; kk < kch; kk += BK) {
    const size_t k0 = k0base + kk;
    // stage A: 128 rows x 32 bf16, 2 rounds x 256 thr x 16 B
    #pragma unroll
    for (int i = 0; i < 2; ++i) {
      const int rr = srow + i * 64;
      const uint4 d = *(const uint4*)(A + (size_t)(mBase + rr) * K_ + k0 + sch * 8);
      *(uint4*)(As + gidx(rr, sch) * 8) = d;
    }
    // stage W: 128 rows x 32 f32 -> bf16, 2 rounds x 256 thr x (32B in, 16B out)
    #pragma unroll
    for (int i = 0; i < 2; ++i) {
      const int rr = srow + i * 64;
      const float* wp = W + (size_t)(nBase + rr) * K_ + k0 + sch * 8;
      const float4 a0 = *(const float4*)(wp);
      const float4 a1 = *(const float4*)(wp + 4);
      shortx8 bfv;
      bfv[0] = (short)f2bf(a0.x); bfv[1] = (short)f2bf(a0.y);
      bfv[2] = (short)f2bf(a0.z); bfv[3] = (short)f2bf(a0.w);
      bfv[4] = (short)f2bf(a1.x); bfv[5] = (short)f2bf(a1.y);
      bfv[6] = (short)f2bf(a1.z); bfv[7] = (short)f2bf(a1.w);
      *(shortx8*)(Ws + gidx(rr, sch) * 8) = bfv;
    }
    __syncthreads();

    shortx8 af[4], wf[4];
    const int fofs = quad * 16 + (lrow ^ (quad << 2));
    #pragma unroll
    for (int ti = 0; ti < 4; ++ti)
      af[ti] = *(const shortx8*)(As + (((wm >> 4) + ti) * 64 + fofs) * 8);
    #pragma unroll
    for (int tj = 0; tj < 4; ++tj)
      wf[tj] = *(const shortx8*)(Ws + (((wn >> 4) + tj) * 64 + fofs) * 8);

    #pragma unroll
    for (int ti = 0; ti < 4; ++ti)
      #pragma unroll
      for (int tj = 0; tj < 4; ++tj)
        acc[ti][tj] = __builtin_amdgcn_mfma_f32_16x16x32_bf16(af[ti], wf[tj], acc[ti][tj], 0, 0, 0);
    __syncthreads();
  }

  // epilogue (D layout: m = quad*4+reg, n = lane&15)
  if (atomic_mode == 0) {
    float* dst = out + (size_t)blockIdx.z * (M_ * OS_);
    #pragma unroll
    for (int ti = 0; ti < 4; ++ti)
      #pragma unroll
      for (int tj = 0; tj < 4; ++tj)
        #pragma unroll
        for (int j = 0; j < 4; ++j) {
          const int m = mBase + wm + ti * 16 + quad * 4 + j;
          const int n = nBase + wn + tj * 16 + lrow;
          dst[(size_t)m * OS_ + n] = acc[ti][tj][j];
        }
  } else {
    #pragma unroll
    for (int ti = 0; ti < 4; ++ti)
      #pragma unroll
      for (int tj = 0; tj < 4; ++tj)
        #pragma unroll
        for (int j = 0; j < 4; ++j) {
          const int m = mBase + wm + ti * 16 + quad * 4 + j;
          const int n = nBase + wn + tj * 16 + lrow;
          atomicAdd(out + (size_t)m * OS_ + n, acc[ti][tj][j]);
        }
  }
}

// out[m][n] = bias[n] + sum_z P[z][m][n]; thread = (m, n-quad of 4)
__global__ __launch_bounds__(256) void reduce_out(
    const float* __restrict__ P, const float* __restrict__ bias,
    float* __restrict__ out, int nz) {
  const int tid = blockIdx.x * 256 + threadIdx.x;   // 16384
  const int n4 = (tid & 63) * 4;
  const int m  = tid >> 6;
  floatx4 s = *(const floatx4*)(bias + n4);
  const float* p = P + (size_t)m * OS_ + n4;
  #pragma unroll 8
  for (int z = 0; z < nz; ++z)
    s += *(const floatx4*)(p + (size_t)z * (M_ * OS_));
  *(floatx4*)(out + (size_t)m * OS_ + n4) = s;
}

extern "C" void kernel_launch(void* const* d_in, const int* in_sizes, int n_in,
                              void* d_out, int out_size, void* d_ws, size_t ws_size,
                              hipStream_t stream) {
  const float* x        = (const float*)d_in[0];
  const int*   rxd_perm = (const int*)d_in[1];
  const int*   e_idx    = (const int*)d_in[2];
  const float* signs    = (const float*)d_in[3];
  const float* W        = (const float*)d_in[4];
  const float* bias     = (const float*)d_in[5];
  float* out = (float*)d_out;

  unsigned short* A = (unsigned short*)d_ws;            // 256 x 131072 bf16 = 67.1 MB
  const size_t A_BYTES = (size_t)M_ * K_ * 2;
  const int ZP = 256;                                   // partial path: KCH=512
  const size_t P_BYTES = (size_t)ZP * M_ * OS_ * 4;     // 67.1 MB
  float* Ppart = (float*)((char*)d_ws + A_BYTES);
  const bool use_part = ws_size >= A_BYTES + P_BYTES;   // host-constant branch

  build_A<<<dim3(B_ * C_ * R_), dim3(512), 0, stream>>>(x, rxd_perm, e_idx, signs, A);

  if (use_part) {
    gemm_splitk<<<dim3(M_ / BM, OS_ / BN, ZP), dim3(256), 0, stream>>>(A, W, Ppart, K_ / ZP, 0);
    reduce_out<<<dim3(64), dim3(256), 0, stream>>>(Ppart, bias, out, ZP);
  } else {
    init_out<<<dim3((OS_ * M_) / 256), dim3(256), 0, stream>>>(bias, out);
    gemm_splitk<<<dim3(M_ / BM, OS_ / BN, 128), dim3(256), 0, stream>>>(A, W, out, K_ / 128, 1);
  }
}